// Round 1
// 131.000 us; speedup vs baseline: 1.0161x; 1.0161x over previous
//
#include <hip/hip_runtime.h>
#include <math.h>

#define T_TOK 16384   // 4*4096 tokens
#define NEXP  64

// Workspace layout (floats):
//   ws[0..63]   : expert load sums
//   ws[64]      : sum of z^2
//   ws[66]      : block-done counter (int)
//   ws[128 ..]  : w_t transposed gate weights [1024][64]
//
// d_out layout (floats, out_size = 65537):
//   [0, 32768)      top-2 renormalized scores [token][2]
//   [32768, 65536)  top-2 expert indices as floats [token][2]
//   [65536]         total_loss

// ---------------------------------------------------------------------------
// prep: tiled transpose gate_w [64][1024] -> w_t [1024][64]; zero accumulators
// ---------------------------------------------------------------------------
__global__ void moe_prep(const float* __restrict__ gw, float* __restrict__ ws) {
    __shared__ float tile[64][65];
    const int b = blockIdx.x;
    const int tid = threadIdx.x;         // 256
    if (b == 0 && tid < 128) ws[tid] = 0.f;
#pragma unroll
    for (int it = 0; it < 16; ++it) {
        int idx = it * 256 + tid;
        int e = idx >> 6, kk = idx & 63;
        tile[e][kk] = gw[e * 1024 + b * 64 + kk];
    }
    __syncthreads();
#pragma unroll
    for (int it = 0; it < 16; ++it) {
        int idx = it * 256 + tid;
        int kk = idx >> 6, e = idx & 63;
        ws[128 + (b * 64 + kk) * 64 + e] = tile[e][kk];
    }
}

// ---------------------------------------------------------------------------
// partial fold helpers: store/add a wave's 64t x 64e partial (8t x 8e per
// lane, token t = tg + 8i, experts eg*8..eg*8+7) into a stride-68 buffer.
// Per instr: 8 consecutive rows at stride 68 (=4 dwords mod 32) -> 8 distinct
// bank-quads, conflict-free.
// ---------------------------------------------------------------------------
__device__ __forceinline__ void pstore(float* B, const float (&a)[8][8],
                                       int tg, int eg) {
#pragma unroll
    for (int i = 0; i < 8; ++i) {
        float* p = B + (tg + 8 * i) * 68 + (eg << 3);
        *(float4*)(p)     = make_float4(a[i][0], a[i][1], a[i][2], a[i][3]);
        *(float4*)(p + 4) = make_float4(a[i][4], a[i][5], a[i][6], a[i][7]);
    }
}
__device__ __forceinline__ void padd(float* B, const float (&a)[8][8],
                                     int tg, int eg) {
#pragma unroll
    for (int i = 0; i < 8; ++i) {
        float* p = B + (tg + 8 * i) * 68 + (eg << 3);
        float4 v0 = *(float4*)(p);
        float4 v1 = *(float4*)(p + 4);
        v0.x += a[i][0]; v0.y += a[i][1]; v0.z += a[i][2]; v0.w += a[i][3];
        v1.x += a[i][4]; v1.y += a[i][5]; v1.z += a[i][6]; v1.w += a[i][7];
        *(float4*)(p)     = v0;
        *(float4*)(p + 4) = v1;
    }
}

// ---------------------------------------------------------------------------
// main: register-tiled fp32 GEMM, 8t x 8e per lane (1.0 B/FMA from LDS, half
// the ds_read_b128 count of the 4x4 version -- the proven LDS-issue
// bottleneck). Block = 64 t x 64 e, 1024 threads = 16 waves; ONE wave covers
// the whole 64x64 tile, waves form a 16-way k-split (wave wv owns k-granule
// wv of each step's 64-k slab). Staging per step: contiguous [64][64] slabs
// of x and w (1 float4/thread each, fully coalesced). All LDS tiles use
// stride 68 so consecutive-row b128 reads hit distinct bank-quads.
// 16 k-partials fold via 3 parallel accumulation buffers (sc/xbuf/wbuf).
// ---------------------------------------------------------------------------
__launch_bounds__(1024, 4)
__global__ void moe_main(const float* __restrict__ x,
                         const float* __restrict__ wt,     // [1024][64]
                         float* __restrict__ acc_ws,
                         float* __restrict__ out) {
    __shared__ float xbuf[64 * 68];      // x slab [t 64][k 64], stride 68
    __shared__ float wbuf[64 * 68];      // w slab [k 64][e 64], stride 68
    __shared__ float sc[64 * 68];        // logits, stride 68
    __shared__ float row_inv[64];
    __shared__ float colpart[16][64];
    __shared__ int   is_last;

    const int tid  = threadIdx.x;
    const int lane = tid & 63;
    const int wv   = __builtin_amdgcn_readfirstlane(tid >> 6);   // 0..15 k-granule
    const int tg   = lane & 7;           // token sub-row: t = tg + 8i
    const int eg   = lane >> 3;          // expert octet: e = eg*8 + j
    const int tok0 = blockIdx.x << 6;

    // ---- staging plan (1024 threads, 1 float4 each for x and w per step)
    const int rr = tid >> 4;             // 0..63 (x: token row / w: k row)
    const int cg = tid & 15;             // granule
    const float* gx = x + (((size_t)(tok0 + rr)) << 10) + (cg << 2);
    const float* gw = wt + (rr << 6) + (cg << 2);
    const int lof = rr * 68 + (cg << 2); // same layout both slabs

    float acc[8][8];
#pragma unroll
    for (int i = 0; i < 8; ++i)
#pragma unroll
        for (int j = 0; j < 8; ++j) acc[i][j] = 0.f;

    // ---- per-lane read bases (constant across steps)
    const float* xr = xbuf + tg * 68 + (wv << 2);        // + i*544 (imm)
    const float* wr = wbuf + (wv * 4) * 68 + (eg << 3);  // + u*68, +4 (imm)

    // prologue prefetch of step 0
    float4 px = *(const float4*)gx;
    float4 pw = *(const float4*)gw;

#pragma unroll 1
    for (int s = 0; s < 16; ++s) {
        __syncthreads();                            // bufs free
        *(float4*)(xbuf + lof) = px;
        *(float4*)(wbuf + lof) = pw;
        __syncthreads();                            // bufs ready
        if (s < 15) {                               // prefetch next step
            px = *(const float4*)(gx + ((s + 1) << 6));     // +64 floats k
            pw = *(const float4*)(gw + ((s + 1) << 12));    // +64 k rows
        }
        // w fragment: 4 k-rows x 8 experts, reused across all 8 token rows
        float wa[4][8];
#pragma unroll
        for (int u = 0; u < 4; ++u) {
            float4 q0 = *(const float4*)(wr + u * 68);
            float4 q1 = *(const float4*)(wr + u * 68 + 4);
            wa[u][0] = q0.x; wa[u][1] = q0.y; wa[u][2] = q0.z; wa[u][3] = q0.w;
            wa[u][4] = q1.x; wa[u][5] = q1.y; wa[u][6] = q1.z; wa[u][7] = q1.w;
        }
#pragma unroll
        for (int i = 0; i < 8; ++i) {
            float4 xc = *(const float4*)(xr + i * 544);     // x[tg+8i][4k]
            float xa[4] = {xc.x, xc.y, xc.z, xc.w};
#pragma unroll
            for (int u = 0; u < 4; ++u) {
                float xv = xa[u];
#pragma unroll
                for (int j = 0; j < 8; ++j)
                    acc[i][j] = fmaf(xv, wa[u][j], acc[i][j]);
            }
        }
    }

    // ---- fold 16 k-partials into sc via 3 accumulation chains
    __syncthreads();                     // step-15 reads done; bufs reusable
    if      (wv == 0) pstore(sc,   acc, tg, eg);
    else if (wv == 1) pstore(xbuf, acc, tg, eg);
    else if (wv == 2) pstore(wbuf, acc, tg, eg);
    __syncthreads();
    if      (wv == 3) padd(sc,   acc, tg, eg);
    else if (wv == 4) padd(xbuf, acc, tg, eg);
    else if (wv == 5) padd(wbuf, acc, tg, eg);
    __syncthreads();
    if      (wv == 6) padd(sc,   acc, tg, eg);
    else if (wv == 7) padd(xbuf, acc, tg, eg);
    else if (wv == 8) padd(wbuf, acc, tg, eg);
    __syncthreads();
    if      (wv == 9)  padd(sc,   acc, tg, eg);
    else if (wv == 10) padd(xbuf, acc, tg, eg);
    else if (wv == 11) padd(wbuf, acc, tg, eg);
    __syncthreads();
    if      (wv == 12) padd(sc,   acc, tg, eg);
    else if (wv == 13) padd(xbuf, acc, tg, eg);
    else if (wv == 14) padd(wbuf, acc, tg, eg);
    __syncthreads();
    if (wv == 15) padd(sc, acc, tg, eg);
    __syncthreads();
    {   // sc += xbuf + wbuf (vectorized, all 1024 threads)
        const int row = tid >> 4, g = tid & 15;
        float* ps = sc + row * 68 + (g << 2);
        float4 a  = *(float4*)ps;
        float4 bx = *(const float4*)(xbuf + row * 68 + (g << 2));
        float4 bw = *(const float4*)(wbuf + row * 68 + (g << 2));
        a.x += bx.x + bw.x; a.y += bx.y + bw.y;
        a.z += bx.z + bw.z; a.w += bx.w + bw.w;
        *(float4*)ps = a;
    }
    __syncthreads();

    // ---- per-token epilogue (serial, proven absmax 0)
    if (tid < 64) {
        const int r = tid;
        const float* srow = sc + r * 68;
        float v1 = -1e30f, v2 = -1e30f;
        int i1 = 0, i2 = 0;
        for (int j = 0; j < 64; ++j) {
            float l = srow[j];
            if (l > v1)      { v2 = v1; i2 = i1; v1 = l; i1 = j; }
            else if (l > v2) { v2 = l; i2 = j; }
        }
        float m = v1;
        float ssum = 0.f;
        for (int j = 0; j < 64; ++j) {
            float ev = expf(srow[j] - m);
            ssum += ev;
            sc[r * 68 + j] = ev;
        }
        float inv = 1.f / ssum;
        row_inv[r] = inv;
        float z = m + logf(ssum);
        float zsq = z * z;
#pragma unroll
        for (int off = 32; off > 0; off >>= 1) zsq += __shfl_down(zsq, off);
        if (lane == 0) atomicAdd(acc_ws + 64, zsq);

        float p1s = inv;                        // exp(v1-m) == 1
        float p2s = expf(v2 - m) * inv;
        float bb  = expf(p2s - p1s);
        float s1 = 1.f / (1.f + bb);
        float s2 = bb * s1;
        int t = tok0 + r;
        out[2 * t]     = s1;
        out[2 * t + 1] = s2;
        out[2 * T_TOK + 2 * t]     = (float)i1;
        out[2 * T_TOK + 2 * t + 1] = (float)i2;
    }
    __syncthreads();

    // ---- expert load column sums (16 row-groups of 4 rows)
    {
        int e  = tid & 63;
        int rg = tid >> 6;                      // 0..15
        float sum = 0.f;
#pragma unroll
        for (int r2 = 0; r2 < 4; ++r2) {
            int row = (rg << 2) + r2;
            sum += sc[row * 68 + e] * row_inv[row];
        }
        colpart[rg][e] = sum;
    }
    __syncthreads();
    if (tid < 64) {
        float tot = 0.f;
#pragma unroll
        for (int rg = 0; rg < 16; ++rg) tot += colpart[rg][tid];
        atomicAdd(acc_ws + tid, tot);           // device-scope
    }

    // ---- last-block finalize
    __syncthreads();
    if (tid == 0) {
        __threadfence();
        int old = __hip_atomic_fetch_add((int*)(acc_ws + 66), 1,
                                         __ATOMIC_ACQ_REL, __HIP_MEMORY_SCOPE_AGENT);
        is_last = (old == 255) ? 1 : 0;
    }
    __syncthreads();
    if (is_last && tid < 64) {
        __threadfence();
        float load = __hip_atomic_load(acc_ws + tid, __ATOMIC_RELAXED,
                                       __HIP_MEMORY_SCOPE_AGENT) * (1.f / 16384.f);
        float d = load - (1.f / 64.f);
        float v = d * d;
#pragma unroll
        for (int off = 32; off > 0; off >>= 1) v += __shfl_down(v, off);
        if (tid == 0) {
            float zsum = __hip_atomic_load(acc_ws + 64, __ATOMIC_RELAXED,
                                           __HIP_MEMORY_SCOPE_AGENT);
            float lb = 0.01f * 64.f * v;
            float zl = 1e-4f * zsum * (1.f / 16384.f);
            out[4 * T_TOK] = lb + zl;
        }
    }
}

extern "C" void kernel_launch(void* const* d_in, const int* in_sizes, int n_in,
                              void* d_out, int out_size, void* d_ws, size_t ws_size,
                              hipStream_t stream) {
    const float* x  = (const float*)d_in[0];   // [4,4096,1024] fp32
    const float* gw = (const float*)d_in[1];   // [64,1024] fp32
    float* out = (float*)d_out;                // 65537 fp32
    float* ws  = (float*)d_ws;

    moe_prep<<<16, 256, 0, stream>>>(gw, ws);
    moe_main<<<256, 1024, 0, stream>>>(x, ws + 128, ws, out);
}